// Round 1
// baseline (3398.837 us; speedup 1.0000x reference)
//
#include <hip/hip_runtime.h>

// Problem constants
#define NB 16384   // batch
#define ND 768     // d_model
#define NF 8192    // features
// GEMM tiles
#define GBK 32
#define LDAP 132   // padded LDS row (floats), keeps 16B alignment

// ---------------------------------------------------------------------------
// beta[f] = b_enc[f] - sum_d dec_bias[d] * W_enc[f][d]
// (folds the x - dec_bias centering into the GEMM bias; exact when dec_bias==0)
__global__ __launch_bounds__(256) void beta_k(const float* __restrict__ W_enc,
                                              const float* __restrict__ b_enc,
                                              const float* __restrict__ dec_bias,
                                              float* __restrict__ beta) {
  int f = blockIdx.x * 4 + (threadIdx.x >> 6);
  int lane = threadIdx.x & 63;
  const float* wr = W_enc + (size_t)f * ND;
  float s = 0.f;
  for (int d = lane; d < ND; d += 64) s += dec_bias[d] * wr[d];
  for (int off = 32; off; off >>= 1) s += __shfl_down(s, off);
  if (lane == 0) beta[f] = b_enc[f] - s;
}

// ---------------------------------------------------------------------------
// generic 32x32 tiled transpose: in[R][C] -> out[C][R]  (R,C multiples of 32)
__global__ __launch_bounds__(256) void transpose_k(const float* __restrict__ in,
                                                   float* __restrict__ out,
                                                   int R, int C) {
  __shared__ float tile[32][33];
  int lx = threadIdx.x & 31;
  int ty = threadIdx.x >> 5;  // 0..7
  int x = blockIdx.x * 32 + lx;
  for (int j = ty; j < 32; j += 8) {
    int y = blockIdx.y * 32 + j;
    tile[j][lx] = in[(size_t)y * C + x];
  }
  __syncthreads();
  int xo = blockIdx.y * 32 + lx;
  for (int j = ty; j < 32; j += 8) {
    int yo = blockIdx.x * 32 + j;
    out[(size_t)yo * R + xo] = tile[lx][j];
  }
}

// ---------------------------------------------------------------------------
// fp32 GEMM: acts[b][f] = relu( sum_k X[b][k]*W[f][k] + beta[f] )
// 128x128 tile, BK=32, 256 threads, 8x8 micro-tile in split 4+4 layout.
__global__ __launch_bounds__(256) void enc_gemm_k(const float* __restrict__ X,
                                                  const float* __restrict__ W,
                                                  const float* __restrict__ beta,
                                                  float* __restrict__ acts) {
  __shared__ float As[GBK][LDAP];
  __shared__ float Bs[GBK][LDAP];
  const int tid = threadIdx.x;
  const int tn = tid & 15, tm = tid >> 4;
  const int brow = blockIdx.y << 7;
  const int bcol = blockIdx.x << 7;
  const int lr = tid >> 3;        // 0..31
  const int lc = (tid & 7) << 2;  // 0,4,...,28
  float acc[8][8] = {};
  const float* Xb = X + (size_t)brow * ND + lc;
  const float* Wb = W + (size_t)bcol * ND + lc;
  for (int kt = 0; kt < ND; kt += GBK) {
#pragma unroll
    for (int i = 0; i < 4; ++i) {
      int r = lr + (i << 5);
      float4 a = *(const float4*)(Xb + (size_t)r * ND + kt);
      float4 w = *(const float4*)(Wb + (size_t)r * ND + kt);
      As[lc + 0][r] = a.x; As[lc + 1][r] = a.y; As[lc + 2][r] = a.z; As[lc + 3][r] = a.w;
      Bs[lc + 0][r] = w.x; Bs[lc + 1][r] = w.y; Bs[lc + 2][r] = w.z; Bs[lc + 3][r] = w.w;
    }
    __syncthreads();
#pragma unroll
    for (int kk = 0; kk < GBK; ++kk) {
      float4 a0 = *(const float4*)&As[kk][tm << 2];
      float4 a1 = *(const float4*)&As[kk][64 + (tm << 2)];
      float4 b0 = *(const float4*)&Bs[kk][tn << 2];
      float4 b1 = *(const float4*)&Bs[kk][64 + (tn << 2)];
      float av[8] = {a0.x, a0.y, a0.z, a0.w, a1.x, a1.y, a1.z, a1.w};
      float bv[8] = {b0.x, b0.y, b0.z, b0.w, b1.x, b1.y, b1.z, b1.w};
#pragma unroll
      for (int ii = 0; ii < 8; ++ii)
#pragma unroll
        for (int jj = 0; jj < 8; ++jj)
          acc[ii][jj] = fmaf(av[ii], bv[jj], acc[ii][jj]);
    }
    __syncthreads();
  }
  float bet[8];
#pragma unroll
  for (int jj = 0; jj < 4; ++jj) {
    bet[jj]     = beta[bcol + (tn << 2) + jj];
    bet[jj + 4] = beta[bcol + 64 + (tn << 2) + jj];
  }
#pragma unroll
  for (int ii = 0; ii < 8; ++ii) {
    int row = brow + ((ii < 4) ? ((tm << 2) + ii) : (64 + (tm << 2) + ii - 4));
    float4 o0 = make_float4(fmaxf(acc[ii][0] + bet[0], 0.f), fmaxf(acc[ii][1] + bet[1], 0.f),
                            fmaxf(acc[ii][2] + bet[2], 0.f), fmaxf(acc[ii][3] + bet[3], 0.f));
    float4 o1 = make_float4(fmaxf(acc[ii][4] + bet[4], 0.f), fmaxf(acc[ii][5] + bet[5], 0.f),
                            fmaxf(acc[ii][6] + bet[6], 0.f), fmaxf(acc[ii][7] + bet[7], 0.f));
    float* op = acts + (size_t)row * NF + bcol;
    *(float4*)(op + (tn << 2)) = o0;
    *(float4*)(op + 64 + (tn << 2)) = o1;
  }
}

// ---------------------------------------------------------------------------
// per-row top-k via 2048-bin histogram radix select on monotonic keys.
// tie-break: larger value first; equal value -> lower index (matches lax.top_k).
// Output sorted descending -> fully deterministic.
__global__ __launch_bounds__(256) void topk_k(const float* __restrict__ acts,
                                              float* __restrict__ vals,
                                              int* __restrict__ idxs,
                                              const int* __restrict__ kptr) {
  const int b = blockIdx.x;
  const int tid = threadIdx.x;
  int k = *kptr; if (k > 64) k = 64; if (k < 1) k = 1;
  __shared__ unsigned int keys[NF];
  __shared__ unsigned int hist[2048];
  __shared__ unsigned long long cands[1024];
  __shared__ unsigned long long sel[64];
  __shared__ unsigned int csum[256];
  __shared__ unsigned int ctr[4];  // 0 selCount, 1 candCount, 2 thrBin, 3 cntAbove
  __shared__ unsigned long long redbuf[4];

  for (int i = tid; i < 2048; i += 256) hist[i] = 0u;
  if (tid < 4) ctr[tid] = 0u;
  __syncthreads();

  const float4* row4 = (const float4*)(acts + (size_t)b * NF);
#pragma unroll
  for (int i = 0; i < 8; ++i) {
    int q = tid + (i << 8);
    float4 v = row4[q];
#pragma unroll
    for (int j = 0; j < 4; ++j) {
      float f = (j == 0) ? v.x : (j == 1) ? v.y : (j == 2) ? v.z : v.w;
      unsigned int u = __float_as_uint(f);
      u = (u & 0x80000000u) ? ~u : (u | 0x80000000u);
      keys[q * 4 + j] = u;
      atomicAdd(&hist[u >> 21], 1u);
    }
  }
  __syncthreads();
  unsigned int local = 0;
#pragma unroll
  for (int j = 0; j < 8; ++j) local += hist[tid * 8 + j];
  csum[tid] = local;
  __syncthreads();
  for (int off = 1; off < 256; off <<= 1) {  // inclusive suffix sum
    unsigned int other = (tid + off < 256) ? csum[tid + off] : 0u;
    __syncthreads();
    csum[tid] += other;
    __syncthreads();
  }
  {
    unsigned int running = (tid < 255) ? csum[tid + 1] : 0u;
    for (int bin = tid * 8 + 7; bin >= tid * 8; --bin) {
      unsigned int prev = running;
      running += hist[bin];
      if (prev < (unsigned)k && running >= (unsigned)k) {
        ctr[2] = (unsigned)bin; ctr[3] = prev;
      }
    }
  }
  __syncthreads();
  const unsigned int thrBin = ctr[2];
  const int cntAbove = (int)ctr[3];
  const int need = k - cntAbove;

  for (int i = 0; i < 32; ++i) {
    int e = tid + (i << 8);
    unsigned int u = keys[e];
    unsigned int bin = u >> 21;
    if (bin > thrBin) {
      unsigned int s = atomicAdd(&ctr[0], 1u);
      sel[s] = ((unsigned long long)u << 13) | (unsigned)(8191 - e);
    } else if (bin == thrBin) {
      unsigned int c = atomicAdd(&ctr[1], 1u);
      if (c < 1024) cands[c] = ((unsigned long long)u << 13) | (unsigned)(8191 - e);
    }
  }
  __syncthreads();
  const int candCount = (int)ctr[1];

  if (candCount <= 1024) {
    for (int r = 0; r < need; ++r) {
      unsigned long long best = 0ull;
      for (int i = tid; i < candCount; i += 256) best = (cands[i] > best) ? cands[i] : best;
      for (int off = 32; off; off >>= 1) {
        unsigned long long o = __shfl_down(best, off);
        best = (o > best) ? o : best;
      }
      if ((tid & 63) == 0) redbuf[tid >> 6] = best;
      __syncthreads();
      if (tid == 0) {
        unsigned long long m = redbuf[0];
        for (int w = 1; w < 4; ++w) m = (redbuf[w] > m) ? redbuf[w] : m;
        redbuf[0] = m;
        sel[cntAbove + r] = m;
      }
      __syncthreads();
      best = redbuf[0];
      for (int i = tid; i < candCount; i += 256)
        if (cands[i] == best) cands[i] = 0ull;
      __syncthreads();
    }
  } else {
    // degenerate: many ties in threshold bin; select directly from keys
    for (int r = 0; r < need; ++r) {
      unsigned long long best = 0ull;
      for (int i = 0; i < 32; ++i) {
        int e = tid + (i << 8);
        unsigned int u = keys[e];
        if ((u >> 21) == thrBin) {
          unsigned long long p = ((unsigned long long)u << 13) | (unsigned)(8191 - e);
          if (p > best) best = p;
        }
      }
      for (int off = 32; off; off >>= 1) {
        unsigned long long o = __shfl_down(best, off);
        best = (o > best) ? o : best;
      }
      if ((tid & 63) == 0) redbuf[tid >> 6] = best;
      __syncthreads();
      if (tid == 0) {
        unsigned long long m = redbuf[0];
        for (int w = 1; w < 4; ++w) m = (redbuf[w] > m) ? redbuf[w] : m;
        redbuf[0] = m;
        sel[cntAbove + r] = m;
      }
      __syncthreads();
      best = redbuf[0];
      int we = 8191 - (int)(best & 0x1FFFull);
      if ((we & 255) == tid) keys[we] = 0u;  // remove winner
      __syncthreads();
    }
  }
  __syncthreads();
  if (tid < k) {
    unsigned long long p = sel[tid];
    int rank = 0;
    for (int j = 0; j < k; ++j) rank += (sel[j] > p) ? 1 : 0;
    unsigned int u = (unsigned int)(p >> 13);
    int e = 8191 - (int)(p & 0x1FFFull);
    unsigned int bits = (u & 0x80000000u) ? (u & 0x7FFFFFFFu) : ~u;
    vals[(size_t)b * 64 + rank] = __uint_as_float(bits);
    idxs[(size_t)b * 64 + rank] = e;
  }
}

// ---------------------------------------------------------------------------
__global__ void zero_k(float4* __restrict__ p, long n) {
  long i = (long)blockIdx.x * blockDim.x + threadIdx.x;
  long stride = (long)gridDim.x * blockDim.x;
  float4 z = make_float4(0.f, 0.f, 0.f, 0.f);
  for (; i < n; i += stride) p[i] = z;
}

__global__ void scatter_k(float* __restrict__ out_sc, const float* __restrict__ vals,
                          const int* __restrict__ idxs, const int* __restrict__ kptr) {
  int k = *kptr; if (k > 64) k = 64;
  int b = blockIdx.x;
  int t = threadIdx.x;
  if (t < k) {
    int f = idxs[(size_t)b * 64 + t];
    out_sc[(size_t)b * NF + f] = vals[(size_t)b * 64 + t];
  }
}

// rec[b][d] = dec_bias[d] + sum_j val_j * WdecT[idx_j][d]
__global__ __launch_bounds__(256) void decode_k(const float* __restrict__ WdecT,
                                                const float* __restrict__ dec_bias,
                                                const float* __restrict__ vals,
                                                const int* __restrict__ idxs,
                                                float* __restrict__ out,
                                                const int* __restrict__ kptr) {
  int k = *kptr; if (k > 64) k = 64;
  int b = blockIdx.x, tid = threadIdx.x;
  __shared__ float sv[64];
  __shared__ int si[64];
  if (tid < k) { sv[tid] = vals[(size_t)b * 64 + tid]; si[tid] = idxs[(size_t)b * 64 + tid]; }
  __syncthreads();
  float a0 = dec_bias[tid];
  float a1 = dec_bias[tid + 256];
  float a2 = dec_bias[tid + 512];
  for (int j = 0; j < k; ++j) {
    const float* w = WdecT + (size_t)si[j] * ND;
    float v = sv[j];
    a0 = fmaf(v, w[tid], a0);
    a1 = fmaf(v, w[tid + 256], a1);
    a2 = fmaf(v, w[tid + 512], a2);
  }
  float* o = out + (size_t)b * ND;
  o[tid] = a0; o[tid + 256] = a1; o[tid + 512] = a2;
}

// ---------------------------------------------------------------------------
extern "C" void kernel_launch(void* const* d_in, const int* in_sizes, int n_in,
                              void* d_out, int out_size, void* d_ws, size_t ws_size,
                              hipStream_t stream) {
  const float* x        = (const float*)d_in[0];
  const float* W_enc    = (const float*)d_in[1];
  const float* b_enc    = (const float*)d_in[2];
  const float* W_dec    = (const float*)d_in[3];
  const float* dec_bias = (const float*)d_in[4];
  const int*   kptr     = (const int*)d_in[5];

  float* out_rec = (float*)d_out;                       // [NB, ND]
  float* out_sc  = (float*)d_out + (size_t)NB * ND;     // [NB, NF] (also acts scratch)

  char* ws = (char*)d_ws;
  float* WdecT = (float*)ws;                            // [NF, ND]   25,165,824 B
  float* vals  = (float*)(ws + 25165824);               // [NB, 64]    4,194,304 B
  int*   idxs  = (int*)(ws + 29360128);                 // [NB, 64]    4,194,304 B
  float* beta  = (float*)(ws + 33554432);               // [NF]           32,768 B

  beta_k<<<NF / 4, 256, 0, stream>>>(W_enc, b_enc, dec_bias, beta);
  transpose_k<<<dim3(NF / 32, ND / 32), 256, 0, stream>>>(W_dec, WdecT, ND, NF);
  enc_gemm_k<<<dim3(NF / 128, NB / 128), 256, 0, stream>>>(x, W_enc, beta, out_sc);
  topk_k<<<NB, 256, 0, stream>>>(out_sc, vals, idxs, kptr);
  zero_k<<<4096, 256, 0, stream>>>((float4*)out_sc, (long)NB * NF / 4);
  scatter_k<<<NB, 64, 0, stream>>>(out_sc, vals, idxs, kptr);
  decode_k<<<NB, 256, 0, stream>>>(WdecT, dec_bias, vals, idxs, out_rec, kptr);
}

// Round 2
// 1150.759 us; speedup vs baseline: 2.9536x; 2.9536x over previous
//
#include <hip/hip_runtime.h>

#define NB 16384
#define ND 768
#define NF 8192

typedef __attribute__((ext_vector_type(8))) short bf16x8;
typedef __attribute__((ext_vector_type(4))) float f32x4;

__device__ inline unsigned short f2bf(float f) {
  unsigned u = __float_as_uint(f);
  unsigned r = (u + 0x7FFFu + ((u >> 16) & 1u)) >> 16;
  return (unsigned short)r;
}

// ---------------------------------------------------------------------------
// convert fp32 -> bf16 plane, 8 elems/thread
__global__ __launch_bounds__(256) void cvt_bf16_k(const float* __restrict__ in,
                                                  unsigned short* __restrict__ out) {
  size_t t = (size_t)blockIdx.x * 256 + threadIdx.x;
  const float4* i4 = (const float4*)in;
  float4 a = i4[t * 2], b = i4[t * 2 + 1];
  ushort4 lo = make_ushort4(f2bf(a.x), f2bf(a.y), f2bf(a.z), f2bf(a.w));
  ushort4 hi = make_ushort4(f2bf(b.x), f2bf(b.y), f2bf(b.z), f2bf(b.w));
  ((ushort4*)out)[t * 2] = lo;
  ((ushort4*)out)[t * 2 + 1] = hi;
}

// ---------------------------------------------------------------------------
// beta[f] = b_enc[f] - sum_d dec_bias[d] * W_enc[f][d]
__global__ __launch_bounds__(256) void beta_k(const float* __restrict__ W_enc,
                                              const float* __restrict__ b_enc,
                                              const float* __restrict__ dec_bias,
                                              float* __restrict__ beta) {
  int f = blockIdx.x * 4 + (threadIdx.x >> 6);
  int lane = threadIdx.x & 63;
  const float* wr = W_enc + (size_t)f * ND;
  float s = 0.f;
  for (int d = lane; d < ND; d += 64) s += dec_bias[d] * wr[d];
  for (int off = 32; off; off >>= 1) s += __shfl_down(s, off);
  if (lane == 0) beta[f] = b_enc[f] - s;
}

// ---------------------------------------------------------------------------
__global__ __launch_bounds__(256) void transpose_k(const float* __restrict__ in,
                                                   float* __restrict__ out,
                                                   int R, int C) {
  __shared__ float tile[32][33];
  int lx = threadIdx.x & 31;
  int ty = threadIdx.x >> 5;
  int x = blockIdx.x * 32 + lx;
  for (int j = ty; j < 32; j += 8) {
    int y = blockIdx.y * 32 + j;
    tile[j][lx] = in[(size_t)y * C + x];
  }
  __syncthreads();
  int xo = blockIdx.y * 32 + lx;
  for (int j = ty; j < 32; j += 8) {
    int yo = blockIdx.x * 32 + j;
    out[(size_t)yo * R + xo] = tile[lx][j];
  }
}

// ---------------------------------------------------------------------------
// bf16 MFMA GEMM: acts_bf16[b][f] = bf16(relu(sum_k Xb[b,k]*Wb[f,k] + beta[f]))
// m97 structure: 128x128 tile, BK=64, global_load_lds(16B), 4 waves (2x2),
// each wave 64x64 via 4x4 frags of mfma_f32_16x16x32_bf16.
__global__ __launch_bounds__(256) void enc_gemm_bf16(
    const unsigned short* __restrict__ Xb, const unsigned short* __restrict__ Wb,
    const float* __restrict__ beta, unsigned short* __restrict__ acts) {
  __shared__ __align__(1024) unsigned short As[128 * 64];
  __shared__ __align__(1024) unsigned short Bs[128 * 64];
  const int tid = threadIdx.x;
  const int wave = tid >> 6, lane = tid & 63;
  const int wm = wave >> 1, wn = wave & 1;
  const int brow = blockIdx.y << 7, bcol = blockIdx.x << 7;

  f32x4 acc[4][4] = {};

  const int srow = tid >> 3;        // 0..31
  const int scol = (tid & 7) << 3;  // 0..56 step 8 (shorts)
  const unsigned short* gA = Xb + (size_t)(brow + srow) * ND + scol;
  const unsigned short* gB = Wb + (size_t)(bcol + srow) * ND + scol;

  for (int kt = 0; kt < ND; kt += 64) {
#pragma unroll
    for (int i = 0; i < 4; ++i) {
      __builtin_amdgcn_global_load_lds(
          (const __attribute__((address_space(1))) void*)(gA + (size_t)(i * 32) * ND + kt),
          (__attribute__((address_space(3))) void*)(As + (i * 32 + wave * 8) * 64), 16, 0, 0);
      __builtin_amdgcn_global_load_lds(
          (const __attribute__((address_space(1))) void*)(gB + (size_t)(i * 32) * ND + kt),
          (__attribute__((address_space(3))) void*)(Bs + (i * 32 + wave * 8) * 64), 16, 0, 0);
    }
    __syncthreads();
#pragma unroll
    for (int kk = 0; kk < 64; kk += 32) {
      const int kof = kk + ((lane >> 4) << 3);
      const int rA = (wm << 6) + (lane & 15);
      const int rB = (wn << 6) + (lane & 15);
      bf16x8 a[4], bvv[4];
#pragma unroll
      for (int m = 0; m < 4; ++m)
        a[m] = *(const bf16x8*)&As[(rA + (m << 4)) * 64 + kof];
#pragma unroll
      for (int n = 0; n < 4; ++n)
        bvv[n] = *(const bf16x8*)&Bs[(rB + (n << 4)) * 64 + kof];
#pragma unroll
      for (int m = 0; m < 4; ++m)
#pragma unroll
        for (int n = 0; n < 4; ++n)
          acc[m][n] = __builtin_amdgcn_mfma_f32_16x16x32_bf16(a[m], bvv[n], acc[m][n], 0, 0, 0);
    }
    __syncthreads();
  }

  const int c0 = bcol + (wn << 6) + (lane & 15);
  const int r0 = brow + (wm << 6) + ((lane >> 4) << 2);
#pragma unroll
  for (int n = 0; n < 4; ++n) {
    float bet = beta[c0 + (n << 4)];
#pragma unroll
    for (int m = 0; m < 4; ++m) {
#pragma unroll
      for (int r = 0; r < 4; ++r) {
        float v = fmaxf(acc[m][n][r] + bet, 0.f);
        acts[(size_t)(r0 + (m << 4) + r) * NF + c0 + (n << 4)] = f2bf(v);
      }
    }
  }
}

// ---------------------------------------------------------------------------
// D1: per row -- exact kth bf16 key (bitwise binary search), candidate list
// (margin 0.2, worst-case-safe), exact fp32 recompute, top-k select
// (val desc, idx asc), fused reconstruction. Writes vals/idxs for D2.
__global__ __launch_bounds__(256) void d1_select_k(
    const unsigned short* __restrict__ acts, const float* __restrict__ x,
    const float* __restrict__ W_enc, const float* __restrict__ beta,
    const float* __restrict__ WdecT, const float* __restrict__ dec_bias,
    const int* __restrict__ kptr,
    float* __restrict__ out_rec, float* __restrict__ g_vals, int* __restrict__ g_idxs) {
  const int b = blockIdx.x, tid = threadIdx.x;
  const int lane = tid & 63, wave = tid >> 6;
  int k = *kptr; k = k < 1 ? 1 : (k > 64 ? 64 : k);

  __shared__ unsigned scan[256];
  __shared__ unsigned short cidx[1024];
  __shared__ float cval[1024];
  __shared__ float selv[64];
  __shared__ int seli[64];
  __shared__ unsigned wred[4];
  __shared__ unsigned long long wred64[4];

  // load this thread's 32 bf16 keys (relu'd acts, sign bit 0 => raw bits monotonic)
  uint4 kv[4];
  {
    const uint4* ar = (const uint4*)(acts + (size_t)b * NF);
#pragma unroll
    for (int i = 0; i < 4; ++i) kv[i] = ar[tid * 4 + i];
  }

  // exact k-th largest key via MSB binary search (15 passes)
  unsigned T = 0;
  for (int bit = 14; bit >= 0; --bit) {
    unsigned probe = T | (1u << bit);
    int c = 0;
#pragma unroll
    for (int i = 0; i < 4; ++i) {
      const unsigned* w = (const unsigned*)&kv[i];
#pragma unroll
      for (int q = 0; q < 4; ++q) {
        c += ((w[q] & 0xFFFFu) >= probe);
        c += ((w[q] >> 16) >= probe);
      }
    }
    for (int off = 32; off; off >>= 1) c += __shfl_down(c, off);
    if (lane == 0) wred[wave] = (unsigned)c;
    __syncthreads();
    unsigned tot = wred[0] + wred[1] + wred[2] + wred[3];
    if (tot >= (unsigned)k) T = probe;
    __syncthreads();
  }

  const float thr = __uint_as_float(T << 16) - 0.2f;

  // candidate count -> block prefix scan -> deterministic f-ordered append
  unsigned mycnt = 0;
#pragma unroll
  for (int i = 0; i < 4; ++i) {
    const unsigned* w = (const unsigned*)&kv[i];
#pragma unroll
    for (int q = 0; q < 4; ++q) {
#pragma unroll
      for (int h = 0; h < 2; ++h) {
        unsigned u = h ? (w[q] >> 16) : (w[q] & 0xFFFFu);
        if (u && __uint_as_float(u << 16) >= thr) ++mycnt;
      }
    }
  }
  scan[tid] = mycnt;
  __syncthreads();
  for (int off = 1; off < 256; off <<= 1) {
    unsigned v = (tid >= off) ? scan[tid - off] : 0u;
    __syncthreads();
    scan[tid] += v;
    __syncthreads();
  }
  unsigned base = scan[tid] - mycnt;
  unsigned n = scan[255];
  if (n > 1024) n = 1024;
#pragma unroll
  for (int i = 0; i < 4; ++i) {
    const unsigned* w = (const unsigned*)&kv[i];
#pragma unroll
    for (int q = 0; q < 4; ++q) {
#pragma unroll
      for (int h = 0; h < 2; ++h) {
        unsigned u = h ? (w[q] >> 16) : (w[q] & 0xFFFFu);
        if (u && __uint_as_float(u << 16) >= thr) {
          if (base < 1024) cidx[base] = (unsigned short)(tid * 32 + i * 8 + q * 2 + h);
          ++base;
        }
      }
    }
  }
  __syncthreads();

  // exact fp32 dot for each candidate (one wave per candidate, round-robin)
  float xr[12];
#pragma unroll
  for (int c = 0; c < 12; ++c) xr[c] = x[(size_t)b * ND + lane + 64 * c];
  for (unsigned j = wave; j < n; j += 4) {
    const int f = cidx[j];
    const float* wr = W_enc + (size_t)f * ND;
    float s = 0.f;
#pragma unroll
    for (int c = 0; c < 12; ++c) s = fmaf(xr[c], wr[lane + 64 * c], s);
    for (int off = 32; off; off >>= 1) s += __shfl_down(s, off);
    if (lane == 0) cval[j] = s + beta[f];
  }
  __syncthreads();

  // top-k selection: k rounds of argmax over packed (relu(val), 8191-f)
  for (int r = 0; r < k; ++r) {
    unsigned long long best = 0ull;
    for (unsigned j = tid; j < n; j += 256) {
      float cv = cval[j];
      unsigned long long p;
      if (cv < -1e29f) p = 0ull;  // marked as taken
      else {
        float pv = fmaxf(cv, 0.f);
        p = (((unsigned long long)__float_as_uint(pv)) << 13) | (unsigned)(8191 - cidx[j]);
      }
      if (p > best) best = p;
    }
    for (int off = 32; off; off >>= 1) {
      unsigned long long o = __shfl_down(best, off);
      if (o > best) best = o;
    }
    if (lane == 0) wred64[wave] = best;
    __syncthreads();
    unsigned long long m = wred64[0];
#pragma unroll
    for (int w = 1; w < 4; ++w)
      if (wred64[w] > m) m = wred64[w];
    if (tid == 0) {
      if (m) { selv[r] = __uint_as_float((unsigned)(m >> 13)); seli[r] = 8191 - (int)(m & 0x1FFFull); }
      else   { selv[r] = 0.f; seli[r] = 0; }
    }
    if (m) {
      int wf = 8191 - (int)(m & 0x1FFFull);
      for (unsigned j = tid; j < n; j += 256)
        if (cidx[j] == (unsigned short)wf) cval[j] = -1e30f;
    }
    __syncthreads();
  }

  // fused reconstruction: rec[d] = dec_bias[d] + sum_r selv[r]*WdecT[seli[r]][d]
#pragma unroll
  for (int c = 0; c < 3; ++c) {
    int d = tid + 256 * c;
    float a = dec_bias[d];
    for (int r = 0; r < k; ++r) a = fmaf(selv[r], WdecT[(size_t)seli[r] * ND + d], a);
    out_rec[(size_t)b * ND + d] = a;
  }
  if (tid < k) {
    g_vals[b * 64 + tid] = selv[tid];
    g_idxs[b * 64 + tid] = seli[tid];
  }
}

// ---------------------------------------------------------------------------
// D2: build each sparse row in LDS (zero + scatter) and stream out coalesced.
__global__ __launch_bounds__(256) void d2_sparse_k(
    const float* __restrict__ g_vals, const int* __restrict__ g_idxs,
    const int* __restrict__ kptr, float* __restrict__ out_sc) {
  const int b = blockIdx.x, tid = threadIdx.x;
  int k = *kptr; k = k < 1 ? 1 : (k > 64 ? 64 : k);
  __shared__ float row[NF];
  __shared__ float sv[64];
  __shared__ int si[64];
  if (tid < k) { sv[tid] = g_vals[b * 64 + tid]; si[tid] = g_idxs[b * 64 + tid]; }
  float4* r4 = (float4*)row;
#pragma unroll
  for (int i = 0; i < 8; ++i) r4[tid + 256 * i] = make_float4(0.f, 0.f, 0.f, 0.f);
  __syncthreads();
  if (tid < k) row[si[tid]] = sv[tid];
  __syncthreads();
  float4* o4 = (float4*)(out_sc + (size_t)b * NF);
#pragma unroll
  for (int i = 0; i < 8; ++i) o4[tid + 256 * i] = r4[tid + 256 * i];
}

// ---------------------------------------------------------------------------
extern "C" void kernel_launch(void* const* d_in, const int* in_sizes, int n_in,
                              void* d_out, int out_size, void* d_ws, size_t ws_size,
                              hipStream_t stream) {
  const float* x        = (const float*)d_in[0];
  const float* W_enc    = (const float*)d_in[1];
  const float* b_enc    = (const float*)d_in[2];
  const float* W_dec    = (const float*)d_in[3];
  const float* dec_bias = (const float*)d_in[4];
  const int*   kptr     = (const int*)d_in[5];

  float* out_rec = (float*)d_out;                    // [NB, ND]
  float* out_sc  = (float*)d_out + (size_t)NB * ND;  // [NB, NF]

  // acts_bf16 in lower half of sparse region; Xbf/Wbf in upper half (dead after GEMM)
  char* scb = (char*)out_sc;
  unsigned short* acts = (unsigned short*)scb;                    // 256 MB
  unsigned short* Xbf  = (unsigned short*)(scb + 268435456);      // 25,165,824 B
  unsigned short* Wbf  = (unsigned short*)(scb + 293601280);      // 12,582,912 B

  char* ws = (char*)d_ws;
  float* WdecT  = (float*)ws;                    // 25,165,824 B
  float* beta   = (float*)(ws + 25165824);       //     32,768 B
  float* g_vals = (float*)(ws + 25198592);       //  4,194,304 B
  int*   g_idxs = (int*)(ws + 29392896);         //  4,194,304 B  (total 33,587,200)

  cvt_bf16_k<<<(NB * ND) / 2048, 256, 0, stream>>>(x, Xbf);
  cvt_bf16_k<<<(NF * ND) / 2048, 256, 0, stream>>>(W_enc, Wbf);
  beta_k<<<NF / 4, 256, 0, stream>>>(W_enc, b_enc, dec_bias, beta);
  transpose_k<<<dim3(NF / 32, ND / 32), 256, 0, stream>>>(W_dec, WdecT, ND, NF);
  enc_gemm_bf16<<<dim3(NF / 128, NB / 128), 256, 0, stream>>>(Xbf, Wbf, beta, acts);
  d1_select_k<<<NB, 256, 0, stream>>>(acts, x, W_enc, beta, WdecT, dec_bias, kptr,
                                      out_rec, g_vals, g_idxs);
  d2_sparse_k<<<NB, 256, 0, stream>>>(g_vals, g_idxs, kptr, out_sc);
}